// Round 7
// baseline (173.269 us; speedup 1.0000x reference)
//
#include <hip/hip_runtime.h>
#include <cstdint>
#include <cstddef>

// Problem constants (from reference setup_inputs)
#define BB   8
#define NN   2048
#define DD   16
#define HHH  64
#define KK   32
#define CAP  96          // max within-R hits kept incl self (mean ~37, Poisson tail safe)
#define FCAP 48          // max fwd neighbors kept (<=32 barring exact d2 ties)
#define DT_C 0.01f
#define R2_C (0.08f * 0.08f)

// 2-D cell grid: 17x17 cells of size R, covering [-0.68, 0.68]^2 (clamped edges)
#define GRID 17
#define NCEL (GRID * GRID)           // 289
#define GOFF 0.68f
#define CINV 12.5f                   // 1/R
#define CSTRIDE 320                  // ints per batch in cellStart

#define WPB   4                 // waves per block (1 particle per wave)
#define BLOCK (WPB * 64)

// Same rounding as the reference's sum-of-squares (sub,sub,mul,mul,add; no fma).
__device__ __forceinline__ float dist2(float px, float py, float qx, float qy) {
    float dx = __fsub_rn(px, qx);
    float dy = __fsub_rn(py, qy);
    return __fadd_rn(__fmul_rn(dx, dx), __fmul_rn(dy, dy));
}

// tanh'(z) = 1 - tanh(z)^2 with tanh computed exactly like XLA-CPU's EmitTanh
// (Eigen fast-tanh rational approx: clamp +/-9, deg-13/deg-6 Horner, divide).
// Used for STEP 0 only: its output x1 feeds step-1 neighbor SELECTION, so it
// must track the reference within ~1 ulp. DO NOT alter this sequence.
__device__ __forceinline__ float dtanh_xla(float zz) {
    float xx = fminf(fmaxf(zz, -9.f), 9.f);
    float x2 = xx * xx;
    float p = fmaf(x2, -2.76076847742355e-16f, 2.00018790482477e-13f);
    p = fmaf(x2, p, -8.60467152213735e-11f);
    p = fmaf(x2, p, 5.12229709037114e-08f);
    p = fmaf(x2, p, 1.48572235717979e-05f);
    p = fmaf(x2, p, 6.37261928875436e-04f);
    p = fmaf(x2, p, 4.89352455891786e-03f);
    p = xx * p;
    float q = fmaf(x2, 1.19825839466702e-06f, 1.18534705686654e-04f);
    q = fmaf(x2, q, 2.26843463243900e-03f);
    q = fmaf(x2, q, 4.89352518554385e-03f);
    float r = __builtin_amdgcn_rcpf(q);
    float t = p * r;
    t = fmaf(fmaf(-q, t, p), r, t);      // one Newton step on the quotient
    return fmaf(-t, t, 1.0f);            // 1 - t^2
}

// Fast sech^2/4 for the FINAL step only: its values never feed a comparison,
// only the output (per-term ~1e-6 error -> output ~1e-8, << 1 bf16 ulp).
// sech^2(z) = 4*e^{-2|z|}/(1+e^{-2|z|})^2 ; returns /4 (folded into 4*v[h]).
__device__ __forceinline__ float s2fast(float z) {
    float a = __builtin_amdgcn_exp2f(-2.885390082f * fabsf(z)); // e^{-2|z|}
    float b = 1.f + a;
    return a * __builtin_amdgcn_rcpf(b * b);
}

// v_mbcnt_lo/hi natively count set bits among lanes BELOW the caller: prefix count.
__device__ __forceinline__ int prefix_cnt(unsigned long long m) {
    return (int)__builtin_amdgcn_mbcnt_hi(
        (unsigned)(m >> 32), __builtin_amdgcn_mbcnt_lo((unsigned)m, 0u));
}

// batch = blk&7 (XCD-aware). Slot assignment is STRIDED across the batch:
// wave w of block b2=blk>>3 handles slot b2 + 512*w. Consecutive sorted slots
// have correlated density (same cell region); striding mixes 4 density strata
// per block -> block durations equalize -> the 2-generation grid's drain tail
// shrinks. Locality cost ~nil (batch sortedPos 16KB + cutArr 8KB are L1-fit).
__device__ __forceinline__ int swizzled_slot(int blk, int w, int& bbase) {
    bbase = (blk & 7) << 11;
    return (blk >> 3) + (NN / WPB) * w;  // strided batch-local sorted slot
}

__device__ __forceinline__ int clampi(int v, int lo, int hi) {
    return v < lo ? lo : (v > hi ? hi : v);
}

// 3x3 cell window of (px,py): three contiguous sorted ranges. Shared by k_cut/k_grad.
struct Win { int rs0, rl0, rs1, rl1, rs2, rl2, tot; };
__device__ __forceinline__ Win cell_window(const int* CS, float px, float py) {
    Win W;
    int cx = clampi((int)((px + GOFF) * CINV), 0, GRID - 1);
    int cy = clampi((int)((py + GOFF) * CINV), 0, GRID - 1);
    int xlo = cx > 0 ? cx - 1 : 0;
    int xhi = cx < GRID - 1 ? cx + 1 : GRID - 1;
    W.rs0 = 0; W.rl0 = 0; W.rs2 = 0; W.rl2 = 0;
    if (cy > 0) {
        int a = CS[(cy - 1) * GRID + xlo], b = CS[(cy - 1) * GRID + xhi + 1];
        W.rs0 = a; W.rl0 = b - a;
    }
    {
        int a = CS[cy * GRID + xlo], b = CS[cy * GRID + xhi + 1];
        W.rs1 = a; W.rl1 = b - a;
    }
    if (cy < GRID - 1) {
        int a = CS[(cy + 1) * GRID + xlo], b = CS[(cy + 1) * GRID + xhi + 1];
        W.rs2 = a; W.rl2 = b - a;
    }
    W.tot = W.rl0 + W.rl1 + W.rl2;
    return W;
}
__device__ __forceinline__ int win_map(const Win& W, int t) {
    int j = W.rs0 + t;
    int u1 = t - W.rl0;
    if (u1 >= 0) j = W.rs1 + u1;
    int u2 = u1 - W.rl1;
    if (u2 >= 0) j = W.rs2 + u2;
    return j;
}

// Per step, one block per batch: counting-sort particles into 17x17 R-cells.
// sortedPos entries are verbatim bit-copies -> d2 values unchanged.
// Block 0 additionally computes v = W2 @ Wout once for the whole step
// (f32 fma chain ascending c == Eigen dot order -> bit-matches the reference).
template <bool FIRST>
__global__ __launch_bounds__(1024) void k_bin(
    const float* __restrict__ x, const float* __restrict__ pos,
    const float* __restrict__ W2, const float* __restrict__ Wout,
    float2* __restrict__ sortedPos, unsigned short* __restrict__ sortedIdx,
    int* __restrict__ cellStart, float* __restrict__ vOut) {
    __shared__ int hist[NCEL], base[NCEL + 1], cursor[NCEL];
    int bat = blockIdx.x, bbase = bat << 11, tid = threadIdx.x;
    if (tid < NCEL) hist[tid] = 0;
    if (blockIdx.x == 0 && tid >= 512 && tid < 512 + HHH) {   // v = W2 @ Wout
        int hh = tid - 512;
        float acc = 0.f;
        for (int c = 0; c < 32; c++) acc = fmaf(W2[hh * 32 + c], Wout[c], acc);
        vOut[hh] = acc;
    }
    __syncthreads();
    float2 q[2]; int cid[2];
#pragma unroll
    for (int u = 0; u < 2; ++u) {
        int i = tid + (u << 10);
        float2 qq = FIRST ? *(const float2*)(x + (size_t)(bbase + i) * DD)
                          : *(const float2*)(pos + (size_t)(bbase + i) * 2);
        q[u] = qq;
        int cx = clampi((int)((qq.x + GOFF) * CINV), 0, GRID - 1);
        int cy = clampi((int)((qq.y + GOFF) * CINV), 0, GRID - 1);
        cid[u] = cy * GRID + cx;
        atomicAdd(&hist[cid[u]], 1);
    }
    __syncthreads();
    if (tid < 64) {             // wave 0: exclusive prefix over 289 bins, 5/lane
        int loc[5], s = 0;
#pragma unroll
        for (int k = 0; k < 5; ++k) {
            int idx = tid * 5 + k;
            loc[k] = (idx < NCEL) ? hist[idx] : 0;
            s += loc[k];
        }
        int pre = s;
#pragma unroll
        for (int off = 1; off < 64; off <<= 1) {
            int t = __shfl_up(pre, off);
            if (tid >= off) pre += t;
        }
        pre -= s;               // exclusive prefix of this lane's first bin
#pragma unroll
        for (int k = 0; k < 5; ++k) {
            int idx = tid * 5 + k;
            if (idx <= NCEL) base[idx] = pre;
            pre += loc[k];
        }
    }
    __syncthreads();
    if (tid < NCEL) cursor[tid] = base[tid];
    if (tid <= NCEL) cellStart[bat * CSTRIDE + tid] = base[tid];
    __syncthreads();
#pragma unroll
    for (int u = 0; u < 2; ++u) {
        int dst = atomicAdd(&cursor[cid[u]], 1);
        sortedPos[bbase + dst] = q[u];
        sortedIdx[bbase + dst] = (unsigned short)(tid + (u << 10));
    }
}

// Kernel 1 per step, one wave per SORTED slot s — barrier-free, cutoff-only:
//  - As = x @ W1[:16], Ds = x @ W1[16:] in f64 (rounded once to f32 planes),
//    4-way split accumulators: dependent-chain 16 -> 4 deep (latency).
//  - scan 3x3 cell window (both iterations' loads issued upfront),
//    collect hit d2's (self included, d2==0 exactly)
//  - cutoff = rank-KK value (0-based incl self); write cutArr[gs]. No emission.
__global__ __launch_bounds__(BLOCK, 4) void k_cut(
    const float* __restrict__ x,
    const float2* __restrict__ sortedPos, const unsigned short* __restrict__ sortedIdx,
    const int* __restrict__ cellStart, const float* __restrict__ W1,
    float* __restrict__ cutArr,
    float* __restrict__ Asp, float* __restrict__ Dsp) {
    __shared__ float sD[WPB][CAP];          // wave-private hit d2's

    int tid = threadIdx.x;
    int w = tid >> 6, lane = tid & 63;
    int bbase;
    int s = swizzled_slot(blockIdx.x, w, bbase);
    int bat = bbase >> 11;
    int gs = bbase + s;                     // global sorted slot

    // ---- A/D precompute (lane = h); W1 direct from global (cache-hot) ----
    int jol = (int)sortedIdx[gs];           // original batch-local id (wave-uniform)
    const float* xrow = x + (size_t)(bbase + jol) * DD;
    float xv = (lane < DD) ? xrow[lane] : 0.f;
    float px = __shfl(xv, 0), py = __shfl(xv, 1);
    // 4-way split f64 accumulators (reassoc noise ~1e-16, far below f32 ulp)
    double A0 = 0.0, A1 = 0.0, A2 = 0.0, A3 = 0.0;
    double D0 = 0.0, D1 = 0.0, D2v = 0.0, D3 = 0.0;
#pragma unroll
    for (int f = 0; f < DD; f += 4) {
        float xf0 = __shfl(xv, f),     xf1 = __shfl(xv, f + 1);
        float xf2 = __shfl(xv, f + 2), xf3 = __shfl(xv, f + 3);
        A0 = fma((double)xf0, (double)W1[(f + 0) * HHH + lane], A0);
        A1 = fma((double)xf1, (double)W1[(f + 1) * HHH + lane], A1);
        A2 = fma((double)xf2, (double)W1[(f + 2) * HHH + lane], A2);
        A3 = fma((double)xf3, (double)W1[(f + 3) * HHH + lane], A3);
        D0 = fma((double)xf0, (double)W1[(DD + f + 0) * HHH + lane], D0);
        D1 = fma((double)xf1, (double)W1[(DD + f + 1) * HHH + lane], D1);
        D2v = fma((double)xf2, (double)W1[(DD + f + 2) * HHH + lane], D2v);
        D3 = fma((double)xf3, (double)W1[(DD + f + 3) * HHH + lane], D3);
    }
    Asp[((size_t)gs << 6) + lane] = (float)((A0 + A1) + (A2 + A3));
    Dsp[((size_t)gs << 6) + lane] = (float)((D0 + D1) + (D2v + D3));

    // ---- candidate scan over 3x3 window (self included) ----
    const int* CS = cellStart + bat * CSTRIDE;
    Win W = cell_window(CS, px, py);
    int cnt = 0;
    {
        int t0 = lane, t1 = 64 + lane;
        bool in0 = t0 < W.tot, in1 = t1 < W.tot;
        int ja0 = in0 ? win_map(W, t0) : 0;
        float2 q0 = sortedPos[bbase + ja0];
        float2 q1;
        bool have1 = W.tot > 64;             // wave-uniform
        if (have1) {
            int ja1 = in1 ? win_map(W, t1) : 0;
            q1 = sortedPos[bbase + ja1];
        }
        float d2 = dist2(px, py, q0.x, q0.y);
        bool hit = in0 && (d2 < R2_C);
        unsigned long long m = __ballot(hit);
        int idx = cnt + prefix_cnt(m);
        if (hit && idx < CAP) sD[w][idx] = d2;
        cnt += (int)__popcll(m);
        if (have1) {
            float e2 = dist2(px, py, q1.x, q1.y);
            bool h2 = in1 && (e2 < R2_C);
            unsigned long long m2 = __ballot(h2);
            int i2 = cnt + prefix_cnt(m2);
            if (h2 && i2 < CAP) sD[w][i2] = e2;
            cnt += (int)__popcll(m2);
        }
        for (int c0 = 128; c0 < W.tot; c0 += 64) {   // rare residual, original path
            int t = c0 + lane;
            int j = win_map(W, t);
            bool in = t < W.tot;
            float2 q = sortedPos[bbase + (in ? j : 0)];
            float dd = dist2(px, py, q.x, q.y);
            bool ht = in && (dd < R2_C);
            unsigned long long mm = __ballot(ht);
            int ix = cnt + prefix_cnt(mm);
            if (ht && ix < CAP) sD[w][ix] = dd;
            cnt += (int)__popcll(mm);
        }
    }
    if (cnt > CAP) cnt = CAP;
    __threadfence_block();   // wave-local LDS RAW drain

    // ---- cutoff = rank-KK value (0-based, incl self) ----
    float cutoff = R2_C;
    if (cnt > KK + 1) {
        const float INF = 1e30f;
        if (cnt <= 64) {
            float v = (lane < cnt) ? sD[w][lane] : INF;
#pragma unroll
            for (int k = 2; k <= 64; k <<= 1) {
#pragma unroll
                for (int j = k >> 1; j > 0; j >>= 1) {
                    float pv = __shfl_xor(v, j);
                    bool up = ((lane & k) == 0);
                    bool takeMin = (((lane & j) == 0) == up);
                    v = takeMin ? fminf(v, pv) : fmaxf(v, pv);
                }
            }
            cutoff = __shfl(v, KK);       // ascending; rank shifted by self
        } else {                          // cnt in (64,96]: ~never, kept for correctness
            float e0 = (lane < cnt) ? sD[w][lane] : INF;
            float e1 = (lane + 64 < cnt) ? sD[w][lane + 64] : INF;
            int r0 = 0, q0 = 0, r1 = 0, q1 = 0;
            for (int k = 0; k < cnt; k++) {
                float val = sD[w][k];
                r0 += (val < e0); q0 += (val == e0);
                r1 += (val < e1); q1 += (val == e1);
            }
            bool c0 = (r0 <= KK) && (r0 + q0 > KK);
            bool c1 = (r1 <= KK) && (r1 + q1 > KK);
            float cand = c0 ? e0 : (c1 ? e1 : INF);
#pragma unroll
            for (int off = 32; off; off >>= 1) cand = fminf(cand, __shfl_xor(cand, off));
            cutoff = cand;
        }
    }
    if (lane == 0) cutArr[gs] = cutoff;
}

// Kernel 2 per step, one wave per SORTED slot s (lane = h):
//  inline scan (both iterations' loads upfront): d2 bit-identical;
//  fwd = d2<=cut_p, rev = d2<=cut_j (self excl), ballot-compact in scan order.
//  EXACT (step 0, feeds selection): dtanh_xla terms, f64 order-invariant sums.
//  !EXACT (final step, feeds only output): s2fast terms, f32 split accs —
//  selection code identical; only term math/acc types differ (output-safe).
template <bool EXACT>
__global__ __launch_bounds__(BLOCK, 4) void k_grad(
    const float* __restrict__ x, const unsigned short* __restrict__ sortedIdx,
    const float2* __restrict__ sortedPos, const int* __restrict__ cellStart,
    const float* __restrict__ cutArr,
    const float* __restrict__ Asp, const float* __restrict__ Dsp,
    const float* __restrict__ W1, const float* __restrict__ b1,
    const float* __restrict__ vArr,
    float* __restrict__ xOut, float* __restrict__ posOut) {
    __shared__ float sW1t[HHH * 33];                       // 8.25 KB
    __shared__ alignas(16) unsigned short sFwd[WPB][FCAP];
    __shared__ alignas(16) unsigned short sRev[WPB][CAP];
    __shared__ float sS[WPB][128];

    int tid = threadIdx.x;
    int w = tid >> 6, h = tid & 63;
    int bbase;
    int s = swizzled_slot(blockIdx.x, w, bbase);
    int bat = bbase >> 11;
    int gs = bbase + s;

    for (int t = tid; t < 2 * DD * HHH; t += BLOCK) {
        int f = t >> 6, hh = t & 63;
        sW1t[hh * 33 + f] = W1[t];            // pad 33: conflict-free write & read
    }
    __syncthreads();                          // the only block barrier

    float b1h = b1[h];
    float Apbs = Asp[((size_t)gs << 6) + h] + b1h;
    float Dpbs = Dsp[((size_t)gs << 6) + h] + b1h;
    float vh = vArr[h];                       // precomputed in k_bin (L2-hot)

    float2 pp = sortedPos[gs];                // verbatim copy of own position
    float px = pp.x, py = pp.y;
    float cutp = cutArr[gs];

    // ---- inline scan: flags from bit-identical d2/cut compares, compacted ----
    const int* CS = cellStart + bat * CSTRIDE;
    Win W = cell_window(CS, px, py);
    int mf = 0, mr = 0;
#define PROC(IN, J, Q, CUTJ)                                              \
    {                                                                     \
        float d2 = dist2(px, py, (Q).x, (Q).y);                           \
        bool hit = (IN) && (d2 < R2_C) && ((J) != s);                     \
        bool fw = hit && (d2 <= cutp);                                    \
        bool rv = hit && (d2 <= (CUTJ));                                  \
        unsigned long long mF = __ballot(fw);                             \
        int iF = mf + prefix_cnt(mF);                                     \
        if (fw && iF < FCAP) sFwd[w][iF] = (unsigned short)(J);           \
        mf += (int)__popcll(mF);                                          \
        unsigned long long mR = __ballot(rv);                             \
        int iR = mr + prefix_cnt(mR);                                     \
        if (rv && iR < CAP) sRev[w][iR] = (unsigned short)(J);            \
        mr += (int)__popcll(mR);                                          \
    }
    {
        int t0 = h, t1 = 64 + h;
        bool in0 = t0 < W.tot, in1 = t1 < W.tot;
        int j0 = win_map(W, t0);
        int ja0 = in0 ? j0 : 0;
        float2 q0 = sortedPos[bbase + ja0];
        float cut0 = cutArr[bbase + ja0];
        bool have1 = W.tot > 64;              // wave-uniform
        int j1 = 0; float2 q1; float cut1 = 0.f;
        if (have1) {
            j1 = win_map(W, t1);
            int ja1 = in1 ? j1 : 0;
            q1 = sortedPos[bbase + ja1];
            cut1 = cutArr[bbase + ja1];
        }
        PROC(in0, j0, q0, cut0)
        if (have1) PROC(in1, j1, q1, cut1)
        for (int c0 = 128; c0 < W.tot; c0 += 64) {   // rare residual, original path
            int t = c0 + h;
            int j = win_map(W, t);
            bool in = t < W.tot;
            int ja = in ? j : 0;
            float2 q = sortedPos[bbase + ja];
            float cutj = cutArr[bbase + ja];
            PROC(in, j, q, cutj)
        }
    }
#undef PROC
    if (mf > FCAP) mf = FCAP;
    if (mr > CAP) mr = CAP;
    __threadfence_block();

    // ---- main loops: branch-free, 16-deep gather batching, scalar row bases ----
    const float* baseD = Dsp + ((size_t)bbase << 6);
    const float* baseA = Asp + ((size_t)bbase << 6);
    double T1 = 0.0, T2 = 0.0;                // EXACT: order-invariant accumulation
    float f1a = 0.f, f1b = 0.f, f2a = 0.f, f2b = 0.f;  // FAST: split f32 accs

#define TERM1(VAL)                                                        \
    { if constexpr (EXACT) T1 += (double)dtanh_xla(Apbs + (VAL));         \
      else { float sv_ = s2fast(Apbs + (VAL));                            \
             if (k & 1) f1b += sv_; else f1a += sv_; } }
#define TERM2(VAL)                                                        \
    { if constexpr (EXACT) T2 += (double)dtanh_xla(Dpbs + (VAL));         \
      else { float sv_ = s2fast(Dpbs + (VAL));                            \
             if (k & 1) f2b += sv_; else f2a += sv_; } }

#define UNPACK8(Q0, Q1, U)                                            \
    unsigned U[8];                                                    \
    U[0] = (unsigned)__builtin_amdgcn_readfirstlane(Q0.x);            \
    U[1] = (unsigned)__builtin_amdgcn_readfirstlane(Q0.y);            \
    U[2] = (unsigned)__builtin_amdgcn_readfirstlane(Q0.z);            \
    U[3] = (unsigned)__builtin_amdgcn_readfirstlane(Q0.w);            \
    U[4] = (unsigned)__builtin_amdgcn_readfirstlane(Q1.x);            \
    U[5] = (unsigned)__builtin_amdgcn_readfirstlane(Q1.y);            \
    U[6] = (unsigned)__builtin_amdgcn_readfirstlane(Q1.z);            \
    U[7] = (unsigned)__builtin_amdgcn_readfirstlane(Q1.w);

    {   // fwd stream
        const unsigned short* L = sFwd[w];
        int c = 0;
        for (; c + 16 <= mf; c += 16) {
            int4 q0 = *(const int4*)(L + c);
            int4 q1 = *(const int4*)(L + c + 8);
            UNPACK8(q0, q1, u)
            float d[16];
#pragma unroll
            for (int k = 0; k < 8; ++k) {     // 16 independent gathers in flight
                const float* ra = baseD + ((size_t)(u[k] & 0xffffu) << 6);
                const float* rb = baseD + ((size_t)(u[k] >> 16) << 6);
                d[2 * k]     = ra[h];
                d[2 * k + 1] = rb[h];
            }
#pragma unroll
            for (int k = 0; k < 16; ++k) TERM1(d[k])
        }
        for (; c + 8 <= mf; c += 8) {
            int4 q0 = *(const int4*)(L + c);
            UNPACK8(q0, q0, u)
            float d[8];
#pragma unroll
            for (int k = 0; k < 4; ++k) {
                const float* ra = baseD + ((size_t)(u[k] & 0xffffu) << 6);
                const float* rb = baseD + ((size_t)(u[k] >> 16) << 6);
                d[2 * k]     = ra[h];
                d[2 * k + 1] = rb[h];
            }
#pragma unroll
            for (int k = 0; k < 8; ++k) TERM1(d[k])
        }
        for (int k = 0; c < mf; ++c, k ^= 1) {
            unsigned jl = (unsigned)__builtin_amdgcn_readfirstlane((int)L[c]);
            TERM1((baseD + ((size_t)jl << 6))[h])
        }
    }
    {   // rev stream
        const unsigned short* L = sRev[w];
        int c = 0;
        for (; c + 16 <= mr; c += 16) {
            int4 q0 = *(const int4*)(L + c);
            int4 q1 = *(const int4*)(L + c + 8);
            UNPACK8(q0, q1, u)
            float d[16];
#pragma unroll
            for (int k = 0; k < 8; ++k) {
                const float* ra = baseA + ((size_t)(u[k] & 0xffffu) << 6);
                const float* rb = baseA + ((size_t)(u[k] >> 16) << 6);
                d[2 * k]     = ra[h];
                d[2 * k + 1] = rb[h];
            }
#pragma unroll
            for (int k = 0; k < 16; ++k) TERM2(d[k])
        }
        for (; c + 8 <= mr; c += 8) {
            int4 q0 = *(const int4*)(L + c);
            UNPACK8(q0, q0, u)
            float d[8];
#pragma unroll
            for (int k = 0; k < 4; ++k) {
                const float* ra = baseA + ((size_t)(u[k] & 0xffffu) << 6);
                const float* rb = baseA + ((size_t)(u[k] >> 16) << 6);
                d[2 * k]     = ra[h];
                d[2 * k + 1] = rb[h];
            }
#pragma unroll
            for (int k = 0; k < 8; ++k) TERM2(d[k])
        }
        for (int k = 0; c < mr; ++c, k ^= 1) {
            unsigned jl = (unsigned)__builtin_amdgcn_readfirstlane((int)L[c]);
            TERM2((baseA + ((size_t)jl << 6))[h])
        }
    }
#undef UNPACK8
#undef TERM1
#undef TERM2

    if constexpr (EXACT) {
        sS[w][h]      = vh * (float)T1;
        sS[w][64 + h] = vh * (float)T2;
    } else {
        float vh4 = 4.f * vh;                 // sech^2 = 4 * s2fast
        sS[w][h]      = vh4 * (f1a + f1b);
        sS[w][64 + h] = vh4 * (f2a + f2b);
    }
    __threadfence_block();                    // wave-local: no block barrier needed

    // full-wave tail: pair (l, l+32) splits each 64-term dot in half.
    float g;
    {
        int col = h & 31;                     // output column (16 fwd + 16 rev)
        const float* Sv = &sS[w][(col < 16) ? 0 : 64];
        int hh0 = (h < 32) ? 0 : 32;          // which half of the 64 terms
        if constexpr (EXACT) {
            double a0 = 0.0, a1 = 0.0, a2 = 0.0, a3 = 0.0;
            for (int hh = hh0; hh < hh0 + 32; hh += 4) {
                a0 = fma((double)sW1t[(hh + 0) * 33 + col], (double)Sv[hh + 0], a0);
                a1 = fma((double)sW1t[(hh + 1) * 33 + col], (double)Sv[hh + 1], a1);
                a2 = fma((double)sW1t[(hh + 2) * 33 + col], (double)Sv[hh + 2], a2);
                a3 = fma((double)sW1t[(hh + 3) * 33 + col], (double)Sv[hh + 3], a3);
            }
            double gd = (a0 + a1) + (a2 + a3);
            double go = __shfl_xor(gd, 32);   // partner half
            g = (float)(gd + go);
        } else {
            float a0 = 0.f, a1 = 0.f, a2 = 0.f, a3 = 0.f;
            for (int hh = hh0; hh < hh0 + 32; hh += 4) {
                a0 = fmaf(sW1t[(hh + 0) * 33 + col], Sv[hh + 0], a0);
                a1 = fmaf(sW1t[(hh + 1) * 33 + col], Sv[hh + 1], a1);
                a2 = fmaf(sW1t[(hh + 2) * 33 + col], Sv[hh + 2], a2);
                a3 = fmaf(sW1t[(hh + 3) * 33 + col], Sv[hh + 3], a3);
            }
            float gd = (a0 + a1) + (a2 + a3);
            float go = __shfl_xor(gd, 32);    // partner half
            g = gd + go;
        }
    }
    float g2 = __shfl(g, (h + 16) & 63);
    int jo = (int)sortedIdx[gs];              // original batch-local id (uniform)
    if (h < DD) {
        size_t prow = (size_t)(bbase + jo) * DD;
        // mirror reference: mul (DT*grad) then sub; block FMA contraction
        float xn = __fsub_rn(x[prow + h], __fmul_rn(DT_C, __fadd_rn(g, g2)));
        xOut[prow + h] = xn;
        if (h < 2) posOut[(bbase + jo) * 2 + h] = xn;
    }
}

extern "C" void kernel_launch(void* const* d_in, const int* in_sizes, int n_in,
                              void* d_out, int out_size, void* d_ws, size_t ws_size,
                              hipStream_t stream) {
    const float* x0   = (const float*)d_in[0];
    const float* W1   = (const float*)d_in[1];
    const float* b1   = (const float*)d_in[2];
    const float* W2   = (const float*)d_in[3];
    const float* Wout = (const float*)d_in[5];
    float* out = (float*)d_out;

    // workspace layout (floats); total ~10 MB
    float* ws   = (float*)d_ws;
    float* posA = ws;                        // 32768 (dead sink for last step)
    float* posB = posA + 32768;              // 32768
    float* x1   = posB + 32768;              // 262144
    float* Asp  = x1 + 262144;               // 16384*64 (4 MB, unscaled)
    float* Dsp  = Asp + 16384 * 64;          // 16384*64 (4 MB, unscaled)
    float* cut  = Dsp + 16384 * 64;          // 16384
    float2* sPosS = (float2*)(cut + 16384);                               // 16384 float2
    unsigned short* sIdx = (unsigned short*)(sPosS + 16384);              // 16384
    int* cellStart = (int*)(sIdx + 16384);                                // 8*320
    float* vArr = (float*)(cellStart + BB * CSTRIDE);                     // 64

    const int NB = (BB * NN) / WPB;          // 4096 blocks x 256 thr

    // step 0: x0 -> x1  (EXACT: x1 feeds step-1 neighbor selection)
    k_bin<true><<<BB, 1024, 0, stream>>>(x0, nullptr, W2, Wout, sPosS, sIdx,
                                         cellStart, vArr);
    k_cut<<<NB, BLOCK, 0, stream>>>(x0, sPosS, sIdx, cellStart, W1, cut, Asp, Dsp);
    k_grad<true><<<NB, BLOCK, 0, stream>>>(x0, sIdx, sPosS, cellStart, cut, Asp, Dsp,
                                           W1, b1, vArr, x1, posB);
    // step 1: x1 -> out  (FAST: values feed only the output, no comparisons)
    k_bin<false><<<BB, 1024, 0, stream>>>(nullptr, posB, W2, Wout, sPosS, sIdx,
                                          cellStart, vArr);
    k_cut<<<NB, BLOCK, 0, stream>>>(x1, sPosS, sIdx, cellStart, W1, cut, Asp, Dsp);
    k_grad<false><<<NB, BLOCK, 0, stream>>>(x1, sIdx, sPosS, cellStart, cut, Asp, Dsp,
                                            W1, b1, vArr, out, posA);
}

// Round 8
// 172.833 us; speedup vs baseline: 1.0025x; 1.0025x over previous
//
#include <hip/hip_runtime.h>
#include <cstdint>
#include <cstddef>

// Problem constants (from reference setup_inputs)
#define BB   8
#define NN   2048
#define DD   16
#define HHH  64
#define KK   32
#define CAP  96          // max within-R hits kept incl self (mean ~37, Poisson tail safe)
#define FCAP 48          // max fwd neighbors kept (<=32 barring exact d2 ties)
#define DT_C 0.01f
#define R2_C (0.08f * 0.08f)

// 2-D cell grid: 17x17 cells of size R, covering [-0.68, 0.68]^2 (clamped edges)
#define GRID 17
#define NCEL (GRID * GRID)           // 289
#define GOFF 0.68f
#define CINV 12.5f                   // 1/R
#define CSTRIDE 320                  // ints per batch in cellStart

#define WPB   4                 // waves per block
#define BLOCK (WPB * 64)

// Same rounding as the reference's sum-of-squares (sub,sub,mul,mul,add; no fma).
__device__ __forceinline__ float dist2(float px, float py, float qx, float qy) {
    float dx = __fsub_rn(px, qx);
    float dy = __fsub_rn(py, qy);
    return __fadd_rn(__fmul_rn(dx, dx), __fmul_rn(dy, dy));
}

// tanh'(z) = 1 - tanh(z)^2 with tanh computed exactly like XLA-CPU's EmitTanh
// (Eigen fast-tanh rational approx: clamp +/-9, deg-13/deg-6 Horner, divide).
// Used for STEP 0 only: its output x1 feeds step-1 neighbor SELECTION, so it
// must track the reference within ~1 ulp. DO NOT alter this sequence.
// (R1/R2 history: one neighbor pair sits ~1e-8 from a cutoff boundary; any
// arithmetic change here re-rolls that die. Numerics are FROZEN.)
__device__ __forceinline__ float dtanh_xla(float zz) {
    float xx = fminf(fmaxf(zz, -9.f), 9.f);
    float x2 = xx * xx;
    float p = fmaf(x2, -2.76076847742355e-16f, 2.00018790482477e-13f);
    p = fmaf(x2, p, -8.60467152213735e-11f);
    p = fmaf(x2, p, 5.12229709037114e-08f);
    p = fmaf(x2, p, 1.48572235717979e-05f);
    p = fmaf(x2, p, 6.37261928875436e-04f);
    p = fmaf(x2, p, 4.89352455891786e-03f);
    p = xx * p;
    float q = fmaf(x2, 1.19825839466702e-06f, 1.18534705686654e-04f);
    q = fmaf(x2, q, 2.26843463243900e-03f);
    q = fmaf(x2, q, 4.89352518554385e-03f);
    float r = __builtin_amdgcn_rcpf(q);
    float t = p * r;
    t = fmaf(fmaf(-q, t, p), r, t);      // one Newton step on the quotient
    return fmaf(-t, t, 1.0f);            // 1 - t^2
}

// Fast sech^2/4 for the FINAL step only: its values never feed a comparison,
// only the output (per-term ~1e-6 error -> output ~1e-8, << 1 bf16 ulp).
// sech^2(z) = 4*e^{-2|z|}/(1+e^{-2|z|})^2 ; returns /4 (folded into 4*v[h]).
__device__ __forceinline__ float s2fast(float z) {
    float a = __builtin_amdgcn_exp2f(-2.885390082f * fabsf(z)); // e^{-2|z|}
    float b = 1.f + a;
    return a * __builtin_amdgcn_rcpf(b * b);
}

// v_mbcnt_lo/hi natively count set bits among lanes BELOW the caller: prefix count.
__device__ __forceinline__ int prefix_cnt(unsigned long long m) {
    return (int)__builtin_amdgcn_mbcnt_hi(
        (unsigned)(m >> 32), __builtin_amdgcn_mbcnt_lo((unsigned)m, 0u));
}

// batch = blk&7 (XCD-aware). Strided slot assignment (R7, neutral-but-harmless).
__device__ __forceinline__ int swizzled_slot(int blk, int w, int& bbase) {
    bbase = (blk & 7) << 11;
    return (blk >> 3) + (NN / WPB) * w;  // strided batch-local sorted slot
}

__device__ __forceinline__ int clampi(int v, int lo, int hi) {
    return v < lo ? lo : (v > hi ? hi : v);
}

// 3x3 cell window of (px,py): three contiguous sorted ranges. Shared by k_cut/k_grad.
struct Win { int rs0, rl0, rs1, rl1, rs2, rl2, tot; };
__device__ __forceinline__ Win cell_window(const int* CS, float px, float py) {
    Win W;
    int cx = clampi((int)((px + GOFF) * CINV), 0, GRID - 1);
    int cy = clampi((int)((py + GOFF) * CINV), 0, GRID - 1);
    int xlo = cx > 0 ? cx - 1 : 0;
    int xhi = cx < GRID - 1 ? cx + 1 : GRID - 1;
    W.rs0 = 0; W.rl0 = 0; W.rs2 = 0; W.rl2 = 0;
    if (cy > 0) {
        int a = CS[(cy - 1) * GRID + xlo], b = CS[(cy - 1) * GRID + xhi + 1];
        W.rs0 = a; W.rl0 = b - a;
    }
    {
        int a = CS[cy * GRID + xlo], b = CS[cy * GRID + xhi + 1];
        W.rs1 = a; W.rl1 = b - a;
    }
    if (cy < GRID - 1) {
        int a = CS[(cy + 1) * GRID + xlo], b = CS[(cy + 1) * GRID + xhi + 1];
        W.rs2 = a; W.rl2 = b - a;
    }
    W.tot = W.rl0 + W.rl1 + W.rl2;
    return W;
}
__device__ __forceinline__ int win_map(const Win& W, int t) {
    int j = W.rs0 + t;
    int u1 = t - W.rl0;
    if (u1 >= 0) j = W.rs1 + u1;
    int u2 = u1 - W.rl1;
    if (u2 >= 0) j = W.rs2 + u2;
    return j;
}

// Per step, one block per batch: counting-sort particles into 17x17 R-cells.
// sortedPos entries are verbatim bit-copies -> d2 values unchanged.
// Block 0 additionally computes v = W2 @ Wout once for the whole step
// (f32 fma chain ascending c == Eigen dot order -> bit-matches the reference).
template <bool FIRST>
__global__ __launch_bounds__(1024) void k_bin(
    const float* __restrict__ x, const float* __restrict__ pos,
    const float* __restrict__ W2, const float* __restrict__ Wout,
    float2* __restrict__ sortedPos, unsigned short* __restrict__ sortedIdx,
    int* __restrict__ cellStart, float* __restrict__ vOut) {
    __shared__ int hist[NCEL], base[NCEL + 1], cursor[NCEL];
    int bat = blockIdx.x, bbase = bat << 11, tid = threadIdx.x;
    if (tid < NCEL) hist[tid] = 0;
    if (blockIdx.x == 0 && tid >= 512 && tid < 512 + HHH) {   // v = W2 @ Wout
        int hh = tid - 512;
        float acc = 0.f;
        for (int c = 0; c < 32; c++) acc = fmaf(W2[hh * 32 + c], Wout[c], acc);
        vOut[hh] = acc;
    }
    __syncthreads();
    float2 q[2]; int cid[2];
#pragma unroll
    for (int u = 0; u < 2; ++u) {
        int i = tid + (u << 10);
        float2 qq = FIRST ? *(const float2*)(x + (size_t)(bbase + i) * DD)
                          : *(const float2*)(pos + (size_t)(bbase + i) * 2);
        q[u] = qq;
        int cx = clampi((int)((qq.x + GOFF) * CINV), 0, GRID - 1);
        int cy = clampi((int)((qq.y + GOFF) * CINV), 0, GRID - 1);
        cid[u] = cy * GRID + cx;
        atomicAdd(&hist[cid[u]], 1);
    }
    __syncthreads();
    if (tid < 64) {             // wave 0: exclusive prefix over 289 bins, 5/lane
        int loc[5], s = 0;
#pragma unroll
        for (int k = 0; k < 5; ++k) {
            int idx = tid * 5 + k;
            loc[k] = (idx < NCEL) ? hist[idx] : 0;
            s += loc[k];
        }
        int pre = s;
#pragma unroll
        for (int off = 1; off < 64; off <<= 1) {
            int t = __shfl_up(pre, off);
            if (tid >= off) pre += t;
        }
        pre -= s;               // exclusive prefix of this lane's first bin
#pragma unroll
        for (int k = 0; k < 5; ++k) {
            int idx = tid * 5 + k;
            if (idx <= NCEL) base[idx] = pre;
            pre += loc[k];
        }
    }
    __syncthreads();
    if (tid < NCEL) cursor[tid] = base[tid];
    if (tid <= NCEL) cellStart[bat * CSTRIDE + tid] = base[tid];
    __syncthreads();
#pragma unroll
    for (int u = 0; u < 2; ++u) {
        int dst = atomicAdd(&cursor[cid[u]], 1);
        sortedPos[bbase + dst] = q[u];
        sortedIdx[bbase + dst] = (unsigned short)(tid + (u << 10));
    }
}

// Kernel 1 per step — TWO particles per wave (slots p and p+1024):
// the two particles' dependent chains (f64 dot, window loads, bitonic) are
// independent -> they hide each other's latency; W1 loads shared between the
// two dots. Per-particle arithmetic sequence is VERBATIM the 1-per-wave
// version -> every Asp/Dsp/cutArr value is bit-identical.
__global__ __launch_bounds__(BLOCK, 4) void k_cut(
    const float* __restrict__ x,
    const float2* __restrict__ sortedPos, const unsigned short* __restrict__ sortedIdx,
    const int* __restrict__ cellStart, const float* __restrict__ W1,
    float* __restrict__ cutArr,
    float* __restrict__ Asp, float* __restrict__ Dsp) {
    __shared__ float sD[WPB][2][CAP];       // two wave-private hit-d2 arrays

    int tid = threadIdx.x;
    int w = tid >> 6, lane = tid & 63;
    int bbase = (blockIdx.x & 7) << 11;
    int bat = bbase >> 11;
    int p = (blockIdx.x >> 3) + (NN / WPB / 2) * w;   // pair index in [0,1024)
    int sA = p, sB = p + (NN / 2);
    int gsA = bbase + sA, gsB = bbase + sB;

    // ---- A/D precompute for BOTH particles; W1 loads shared ----
    int jolA = (int)sortedIdx[gsA];
    int jolB = (int)sortedIdx[gsB];
    const float* xrowA = x + (size_t)(bbase + jolA) * DD;
    const float* xrowB = x + (size_t)(bbase + jolB) * DD;
    float xvA = (lane < DD) ? xrowA[lane] : 0.f;
    float xvB = (lane < DD) ? xrowB[lane] : 0.f;
    float pxA = __shfl(xvA, 0), pyA = __shfl(xvA, 1);
    float pxB = __shfl(xvB, 0), pyB = __shfl(xvB, 1);
    // 4-way split f64 accumulators per particle — same split/order as before,
    // so the f64 sums (and their single f32 rounding) are bit-identical.
    double AA0 = 0.0, AA1 = 0.0, AA2 = 0.0, AA3 = 0.0;
    double DA0 = 0.0, DA1 = 0.0, DA2 = 0.0, DA3 = 0.0;
    double AB0 = 0.0, AB1 = 0.0, AB2 = 0.0, AB3 = 0.0;
    double DB0 = 0.0, DB1 = 0.0, DB2 = 0.0, DB3 = 0.0;
#pragma unroll
    for (int f = 0; f < DD; f += 4) {
        float w0 = W1[(f + 0) * HHH + lane], w1 = W1[(f + 1) * HHH + lane];
        float w2 = W1[(f + 2) * HHH + lane], w3 = W1[(f + 3) * HHH + lane];
        float v0 = W1[(DD + f + 0) * HHH + lane], v1 = W1[(DD + f + 1) * HHH + lane];
        float v2 = W1[(DD + f + 2) * HHH + lane], v3 = W1[(DD + f + 3) * HHH + lane];
        float a0 = __shfl(xvA, f),     a1 = __shfl(xvA, f + 1);
        float a2 = __shfl(xvA, f + 2), a3 = __shfl(xvA, f + 3);
        float b0 = __shfl(xvB, f),     b1 = __shfl(xvB, f + 1);
        float b2 = __shfl(xvB, f + 2), b3 = __shfl(xvB, f + 3);
        AA0 = fma((double)a0, (double)w0, AA0);
        AA1 = fma((double)a1, (double)w1, AA1);
        AA2 = fma((double)a2, (double)w2, AA2);
        AA3 = fma((double)a3, (double)w3, AA3);
        DA0 = fma((double)a0, (double)v0, DA0);
        DA1 = fma((double)a1, (double)v1, DA1);
        DA2 = fma((double)a2, (double)v2, DA2);
        DA3 = fma((double)a3, (double)v3, DA3);
        AB0 = fma((double)b0, (double)w0, AB0);
        AB1 = fma((double)b1, (double)w1, AB1);
        AB2 = fma((double)b2, (double)w2, AB2);
        AB3 = fma((double)b3, (double)w3, AB3);
        DB0 = fma((double)b0, (double)v0, DB0);
        DB1 = fma((double)b1, (double)v1, DB1);
        DB2 = fma((double)b2, (double)v2, DB2);
        DB3 = fma((double)b3, (double)v3, DB3);
    }
    Asp[((size_t)gsA << 6) + lane] = (float)((AA0 + AA1) + (AA2 + AA3));
    Dsp[((size_t)gsA << 6) + lane] = (float)((DA0 + DA1) + (DA2 + DA3));
    Asp[((size_t)gsB << 6) + lane] = (float)((AB0 + AB1) + (AB2 + AB3));
    Dsp[((size_t)gsB << 6) + lane] = (float)((DB0 + DB1) + (DB2 + DB3));

    // ---- candidate scans (self included); same per-particle order ----
    const int* CS = cellStart + bat * CSTRIDE;
    Win WA = cell_window(CS, pxA, pyA);
    Win WB = cell_window(CS, pxB, pyB);

    auto scan = [&](float px, float py, const Win& W, float* sDrow) -> int {
        int cnt = 0;
        int t0 = lane, t1 = 64 + lane;
        bool in0 = t0 < W.tot, in1 = t1 < W.tot;
        int ja0 = in0 ? win_map(W, t0) : 0;
        float2 q0 = sortedPos[bbase + ja0];
        float2 q1;
        bool have1 = W.tot > 64;             // wave-uniform
        if (have1) {
            int ja1 = in1 ? win_map(W, t1) : 0;
            q1 = sortedPos[bbase + ja1];
        }
        float d2 = dist2(px, py, q0.x, q0.y);
        bool hit = in0 && (d2 < R2_C);
        unsigned long long m = __ballot(hit);
        int idx = cnt + prefix_cnt(m);
        if (hit && idx < CAP) sDrow[idx] = d2;
        cnt += (int)__popcll(m);
        if (have1) {
            float e2 = dist2(px, py, q1.x, q1.y);
            bool h2 = in1 && (e2 < R2_C);
            unsigned long long m2 = __ballot(h2);
            int i2 = cnt + prefix_cnt(m2);
            if (h2 && i2 < CAP) sDrow[i2] = e2;
            cnt += (int)__popcll(m2);
        }
        for (int c0 = 128; c0 < W.tot; c0 += 64) {   // rare residual
            int t = c0 + lane;
            int j = win_map(W, t);
            bool in = t < W.tot;
            float2 q = sortedPos[bbase + (in ? j : 0)];
            float dd = dist2(px, py, q.x, q.y);
            bool ht = in && (dd < R2_C);
            unsigned long long mm = __ballot(ht);
            int ix = cnt + prefix_cnt(mm);
            if (ht && ix < CAP) sDrow[ix] = dd;
            cnt += (int)__popcll(mm);
        }
        return cnt;
    };
    int cntA = scan(pxA, pyA, WA, sD[w][0]);
    int cntB = scan(pxB, pyB, WB, sD[w][1]);
    if (cntA > CAP) cntA = CAP;
    if (cntB > CAP) cntB = CAP;
    __threadfence_block();   // wave-local LDS RAW drain

    // ---- cutoffs = rank-KK values; combined bitonic hides chain latency ----
    const float INF = 1e30f;
    float cutoffA = R2_C, cutoffB = R2_C;
    bool bA = (cntA > KK + 1) && (cntA <= 64);
    bool bB = (cntB > KK + 1) && (cntB <= 64);
    if (bA || bB) {
        // padding identical to the 1-particle version -> same sorted sequence
        float vA = (bA && lane < cntA) ? sD[w][0][lane] : INF;
        float vB = (bB && lane < cntB) ? sD[w][1][lane] : INF;
#pragma unroll
        for (int k = 2; k <= 64; k <<= 1) {
#pragma unroll
            for (int j = k >> 1; j > 0; j >>= 1) {
                float pA = __shfl_xor(vA, j);
                float pB = __shfl_xor(vB, j);
                bool up = ((lane & k) == 0);
                bool takeMin = (((lane & j) == 0) == up);
                vA = takeMin ? fminf(vA, pA) : fmaxf(vA, pA);
                vB = takeMin ? fminf(vB, pB) : fmaxf(vB, pB);
            }
        }
        if (bA) cutoffA = __shfl(vA, KK);
        if (bB) cutoffB = __shfl(vB, KK);
    }
    // cnt in (64,96]: ~never, kept for correctness (original rank-count path)
#define BIGSEL(CNT, ROW, OUT)                                             \
    if ((CNT) > 64) {                                                     \
        float e0 = (lane < (CNT)) ? sD[w][ROW][lane] : INF;               \
        float e1 = (lane + 64 < (CNT)) ? sD[w][ROW][lane + 64] : INF;     \
        int r0 = 0, q0 = 0, r1 = 0, q1 = 0;                               \
        for (int k = 0; k < (CNT); k++) {                                 \
            float val = sD[w][ROW][k];                                    \
            r0 += (val < e0); q0 += (val == e0);                          \
            r1 += (val < e1); q1 += (val == e1);                          \
        }                                                                 \
        bool c0 = (r0 <= KK) && (r0 + q0 > KK);                           \
        bool c1 = (r1 <= KK) && (r1 + q1 > KK);                           \
        float cand = c0 ? e0 : (c1 ? e1 : INF);                           \
        _Pragma("unroll")                                                 \
        for (int off = 32; off; off >>= 1) cand = fminf(cand, __shfl_xor(cand, off)); \
        OUT = cand;                                                       \
    }
    BIGSEL(cntA, 0, cutoffA)
    BIGSEL(cntB, 1, cutoffB)
#undef BIGSEL
    if (lane == 0) {
        cutArr[gsA] = cutoffA;
        cutArr[gsB] = cutoffB;
    }
}

// Kernel 2 per step, one wave per SORTED slot s (lane = h):
//  inline scan (both iterations' loads upfront): d2 bit-identical;
//  fwd = d2<=cut_p, rev = d2<=cut_j (self excl), ballot-compact in scan order.
//  EXACT (step 0, feeds selection): dtanh_xla terms, f64 order-invariant sums.
//  !EXACT (final step, feeds only output): s2fast terms, f32 split accs.
template <bool EXACT>
__global__ __launch_bounds__(BLOCK, 4) void k_grad(
    const float* __restrict__ x, const unsigned short* __restrict__ sortedIdx,
    const float2* __restrict__ sortedPos, const int* __restrict__ cellStart,
    const float* __restrict__ cutArr,
    const float* __restrict__ Asp, const float* __restrict__ Dsp,
    const float* __restrict__ W1, const float* __restrict__ b1,
    const float* __restrict__ vArr,
    float* __restrict__ xOut, float* __restrict__ posOut) {
    __shared__ float sW1t[HHH * 33];                       // 8.25 KB
    __shared__ alignas(16) unsigned short sFwd[WPB][FCAP];
    __shared__ alignas(16) unsigned short sRev[WPB][CAP];
    __shared__ float sS[WPB][128];

    int tid = threadIdx.x;
    int w = tid >> 6, h = tid & 63;
    int bbase;
    int s = swizzled_slot(blockIdx.x, w, bbase);
    int bat = bbase >> 11;
    int gs = bbase + s;

    for (int t = tid; t < 2 * DD * HHH; t += BLOCK) {
        int f = t >> 6, hh = t & 63;
        sW1t[hh * 33 + f] = W1[t];            // pad 33: conflict-free write & read
    }
    __syncthreads();                          // the only block barrier

    float b1h = b1[h];
    float Apbs = Asp[((size_t)gs << 6) + h] + b1h;
    float Dpbs = Dsp[((size_t)gs << 6) + h] + b1h;
    float vh = vArr[h];                       // precomputed in k_bin (L2-hot)

    float2 pp = sortedPos[gs];                // verbatim copy of own position
    float px = pp.x, py = pp.y;
    float cutp = cutArr[gs];

    // ---- inline scan: flags from bit-identical d2/cut compares, compacted ----
    const int* CS = cellStart + bat * CSTRIDE;
    Win W = cell_window(CS, px, py);
    int mf = 0, mr = 0;
#define PROC(IN, J, Q, CUTJ)                                              \
    {                                                                     \
        float d2 = dist2(px, py, (Q).x, (Q).y);                           \
        bool hit = (IN) && (d2 < R2_C) && ((J) != s);                     \
        bool fw = hit && (d2 <= cutp);                                    \
        bool rv = hit && (d2 <= (CUTJ));                                  \
        unsigned long long mF = __ballot(fw);                             \
        int iF = mf + prefix_cnt(mF);                                     \
        if (fw && iF < FCAP) sFwd[w][iF] = (unsigned short)(J);           \
        mf += (int)__popcll(mF);                                          \
        unsigned long long mR = __ballot(rv);                             \
        int iR = mr + prefix_cnt(mR);                                     \
        if (rv && iR < CAP) sRev[w][iR] = (unsigned short)(J);            \
        mr += (int)__popcll(mR);                                          \
    }
    {
        int t0 = h, t1 = 64 + h;
        bool in0 = t0 < W.tot, in1 = t1 < W.tot;
        int j0 = win_map(W, t0);
        int ja0 = in0 ? j0 : 0;
        float2 q0 = sortedPos[bbase + ja0];
        float cut0 = cutArr[bbase + ja0];
        bool have1 = W.tot > 64;              // wave-uniform
        int j1 = 0; float2 q1; float cut1 = 0.f;
        if (have1) {
            j1 = win_map(W, t1);
            int ja1 = in1 ? j1 : 0;
            q1 = sortedPos[bbase + ja1];
            cut1 = cutArr[bbase + ja1];
        }
        PROC(in0, j0, q0, cut0)
        if (have1) PROC(in1, j1, q1, cut1)
        for (int c0 = 128; c0 < W.tot; c0 += 64) {   // rare residual, original path
            int t = c0 + h;
            int j = win_map(W, t);
            bool in = t < W.tot;
            int ja = in ? j : 0;
            float2 q = sortedPos[bbase + ja];
            float cutj = cutArr[bbase + ja];
            PROC(in, j, q, cutj)
        }
    }
#undef PROC
    if (mf > FCAP) mf = FCAP;
    if (mr > CAP) mr = CAP;
    __threadfence_block();

    // ---- main loops: branch-free, 16-deep gather batching, scalar row bases ----
    const float* baseD = Dsp + ((size_t)bbase << 6);
    const float* baseA = Asp + ((size_t)bbase << 6);
    double T1 = 0.0, T2 = 0.0;                // EXACT: order-invariant accumulation
    float f1a = 0.f, f1b = 0.f, f2a = 0.f, f2b = 0.f;  // FAST: split f32 accs

#define TERM1(VAL)                                                        \
    { if constexpr (EXACT) T1 += (double)dtanh_xla(Apbs + (VAL));         \
      else { float sv_ = s2fast(Apbs + (VAL));                            \
             if (k & 1) f1b += sv_; else f1a += sv_; } }
#define TERM2(VAL)                                                        \
    { if constexpr (EXACT) T2 += (double)dtanh_xla(Dpbs + (VAL));         \
      else { float sv_ = s2fast(Dpbs + (VAL));                            \
             if (k & 1) f2b += sv_; else f2a += sv_; } }

#define UNPACK8(Q0, Q1, U)                                            \
    unsigned U[8];                                                    \
    U[0] = (unsigned)__builtin_amdgcn_readfirstlane(Q0.x);            \
    U[1] = (unsigned)__builtin_amdgcn_readfirstlane(Q0.y);            \
    U[2] = (unsigned)__builtin_amdgcn_readfirstlane(Q0.z);            \
    U[3] = (unsigned)__builtin_amdgcn_readfirstlane(Q0.w);            \
    U[4] = (unsigned)__builtin_amdgcn_readfirstlane(Q1.x);            \
    U[5] = (unsigned)__builtin_amdgcn_readfirstlane(Q1.y);            \
    U[6] = (unsigned)__builtin_amdgcn_readfirstlane(Q1.z);            \
    U[7] = (unsigned)__builtin_amdgcn_readfirstlane(Q1.w);

    {   // fwd stream
        const unsigned short* L = sFwd[w];
        int c = 0;
        for (; c + 16 <= mf; c += 16) {
            int4 q0 = *(const int4*)(L + c);
            int4 q1 = *(const int4*)(L + c + 8);
            UNPACK8(q0, q1, u)
            float d[16];
#pragma unroll
            for (int k = 0; k < 8; ++k) {     // 16 independent gathers in flight
                const float* ra = baseD + ((size_t)(u[k] & 0xffffu) << 6);
                const float* rb = baseD + ((size_t)(u[k] >> 16) << 6);
                d[2 * k]     = ra[h];
                d[2 * k + 1] = rb[h];
            }
#pragma unroll
            for (int k = 0; k < 16; ++k) TERM1(d[k])
        }
        for (; c + 8 <= mf; c += 8) {
            int4 q0 = *(const int4*)(L + c);
            UNPACK8(q0, q0, u)
            float d[8];
#pragma unroll
            for (int k = 0; k < 4; ++k) {
                const float* ra = baseD + ((size_t)(u[k] & 0xffffu) << 6);
                const float* rb = baseD + ((size_t)(u[k] >> 16) << 6);
                d[2 * k]     = ra[h];
                d[2 * k + 1] = rb[h];
            }
#pragma unroll
            for (int k = 0; k < 8; ++k) TERM1(d[k])
        }
        for (int k = 0; c < mf; ++c, k ^= 1) {
            unsigned jl = (unsigned)__builtin_amdgcn_readfirstlane((int)L[c]);
            TERM1((baseD + ((size_t)jl << 6))[h])
        }
    }
    {   // rev stream
        const unsigned short* L = sRev[w];
        int c = 0;
        for (; c + 16 <= mr; c += 16) {
            int4 q0 = *(const int4*)(L + c);
            int4 q1 = *(const int4*)(L + c + 8);
            UNPACK8(q0, q1, u)
            float d[16];
#pragma unroll
            for (int k = 0; k < 8; ++k) {
                const float* ra = baseA + ((size_t)(u[k] & 0xffffu) << 6);
                const float* rb = baseA + ((size_t)(u[k] >> 16) << 6);
                d[2 * k]     = ra[h];
                d[2 * k + 1] = rb[h];
            }
#pragma unroll
            for (int k = 0; k < 16; ++k) TERM2(d[k])
        }
        for (; c + 8 <= mr; c += 8) {
            int4 q0 = *(const int4*)(L + c);
            UNPACK8(q0, q0, u)
            float d[8];
#pragma unroll
            for (int k = 0; k < 4; ++k) {
                const float* ra = baseA + ((size_t)(u[k] & 0xffffu) << 6);
                const float* rb = baseA + ((size_t)(u[k] >> 16) << 6);
                d[2 * k]     = ra[h];
                d[2 * k + 1] = rb[h];
            }
#pragma unroll
            for (int k = 0; k < 8; ++k) TERM2(d[k])
        }
        for (int k = 0; c < mr; ++c, k ^= 1) {
            unsigned jl = (unsigned)__builtin_amdgcn_readfirstlane((int)L[c]);
            TERM2((baseA + ((size_t)jl << 6))[h])
        }
    }
#undef UNPACK8
#undef TERM1
#undef TERM2

    if constexpr (EXACT) {
        sS[w][h]      = vh * (float)T1;
        sS[w][64 + h] = vh * (float)T2;
    } else {
        float vh4 = 4.f * vh;                 // sech^2 = 4 * s2fast
        sS[w][h]      = vh4 * (f1a + f1b);
        sS[w][64 + h] = vh4 * (f2a + f2b);
    }
    __threadfence_block();                    // wave-local: no block barrier needed

    // full-wave tail: pair (l, l+32) splits each 64-term dot in half.
    float g;
    {
        int col = h & 31;                     // output column (16 fwd + 16 rev)
        const float* Sv = &sS[w][(col < 16) ? 0 : 64];
        int hh0 = (h < 32) ? 0 : 32;          // which half of the 64 terms
        if constexpr (EXACT) {
            double a0 = 0.0, a1 = 0.0, a2 = 0.0, a3 = 0.0;
            for (int hh = hh0; hh < hh0 + 32; hh += 4) {
                a0 = fma((double)sW1t[(hh + 0) * 33 + col], (double)Sv[hh + 0], a0);
                a1 = fma((double)sW1t[(hh + 1) * 33 + col], (double)Sv[hh + 1], a1);
                a2 = fma((double)sW1t[(hh + 2) * 33 + col], (double)Sv[hh + 2], a2);
                a3 = fma((double)sW1t[(hh + 3) * 33 + col], (double)Sv[hh + 3], a3);
            }
            double gd = (a0 + a1) + (a2 + a3);
            double go = __shfl_xor(gd, 32);   // partner half
            g = (float)(gd + go);
        } else {
            float a0 = 0.f, a1 = 0.f, a2 = 0.f, a3 = 0.f;
            for (int hh = hh0; hh < hh0 + 32; hh += 4) {
                a0 = fmaf(sW1t[(hh + 0) * 33 + col], Sv[hh + 0], a0);
                a1 = fmaf(sW1t[(hh + 1) * 33 + col], Sv[hh + 1], a1);
                a2 = fmaf(sW1t[(hh + 2) * 33 + col], Sv[hh + 2], a2);
                a3 = fmaf(sW1t[(hh + 3) * 33 + col], Sv[hh + 3], a3);
            }
            float gd = (a0 + a1) + (a2 + a3);
            float go = __shfl_xor(gd, 32);    // partner half
            g = gd + go;
        }
    }
    float g2 = __shfl(g, (h + 16) & 63);
    int jo = (int)sortedIdx[gs];              // original batch-local id (uniform)
    if (h < DD) {
        size_t prow = (size_t)(bbase + jo) * DD;
        // mirror reference: mul (DT*grad) then sub; block FMA contraction
        float xn = __fsub_rn(x[prow + h], __fmul_rn(DT_C, __fadd_rn(g, g2)));
        xOut[prow + h] = xn;
        if (h < 2) posOut[(bbase + jo) * 2 + h] = xn;
    }
}

extern "C" void kernel_launch(void* const* d_in, const int* in_sizes, int n_in,
                              void* d_out, int out_size, void* d_ws, size_t ws_size,
                              hipStream_t stream) {
    const float* x0   = (const float*)d_in[0];
    const float* W1   = (const float*)d_in[1];
    const float* b1   = (const float*)d_in[2];
    const float* W2   = (const float*)d_in[3];
    const float* Wout = (const float*)d_in[5];
    float* out = (float*)d_out;

    // workspace layout (floats); total ~10 MB
    float* ws   = (float*)d_ws;
    float* posA = ws;                        // 32768 (dead sink for last step)
    float* posB = posA + 32768;              // 32768
    float* x1   = posB + 32768;              // 262144
    float* Asp  = x1 + 262144;               // 16384*64 (4 MB, unscaled)
    float* Dsp  = Asp + 16384 * 64;          // 16384*64 (4 MB, unscaled)
    float* cut  = Dsp + 16384 * 64;          // 16384
    float2* sPosS = (float2*)(cut + 16384);                               // 16384 float2
    unsigned short* sIdx = (unsigned short*)(sPosS + 16384);              // 16384
    int* cellStart = (int*)(sIdx + 16384);                                // 8*320
    float* vArr = (float*)(cellStart + BB * CSTRIDE);                     // 64

    const int NB  = (BB * NN) / WPB;         // 4096 blocks x 256 thr (k_grad)
    const int NBC = (BB * NN) / (WPB * 2);   // 2048 blocks x 256 thr (k_cut, 2/wave)

    // step 0: x0 -> x1  (EXACT: x1 feeds step-1 neighbor selection)
    k_bin<true><<<BB, 1024, 0, stream>>>(x0, nullptr, W2, Wout, sPosS, sIdx,
                                         cellStart, vArr);
    k_cut<<<NBC, BLOCK, 0, stream>>>(x0, sPosS, sIdx, cellStart, W1, cut, Asp, Dsp);
    k_grad<true><<<NB, BLOCK, 0, stream>>>(x0, sIdx, sPosS, cellStart, cut, Asp, Dsp,
                                           W1, b1, vArr, x1, posB);
    // step 1: x1 -> out  (FAST: values feed only the output, no comparisons)
    k_bin<false><<<BB, 1024, 0, stream>>>(nullptr, posB, W2, Wout, sPosS, sIdx,
                                          cellStart, vArr);
    k_cut<<<NBC, BLOCK, 0, stream>>>(x1, sPosS, sIdx, cellStart, W1, cut, Asp, Dsp);
    k_grad<false><<<NB, BLOCK, 0, stream>>>(x1, sIdx, sPosS, cellStart, cut, Asp, Dsp,
                                            W1, b1, vArr, out, posA);
}